// Round 10
// baseline (598.877 us; speedup 1.0000x reference)
//
#include <hip/hip_runtime.h>
#include <hip/hip_bf16.h>

// DLRM forward: 2 dispatches. wconv (+zero barrier words) then ONE mega
// kernel, 512 blocks co-resident, hand-rolled agent-scope grid barriers.
// B=2048, dense 13, emb 26x100000x64, 27 feats -> 351 pairs,
// top MLP 415(->448)->1024->512->256->1 sigmoid.

#define BATCH 2048
#define VOCAB 100000
#define NSPARSE 26
#define NPAIR 351
#define RLD 448
#define GRIDSZ 512

typedef __attribute__((ext_vector_type(8))) __bf16 bf16x8;
typedef __attribute__((ext_vector_type(4))) float f32x4;
typedef __hip_bfloat16 bf16;

#define GLOAD16(g, l)                                                          \
    __builtin_amdgcn_global_load_lds(                                          \
        (const __attribute__((address_space(1))) unsigned int*)(g),            \
        (__attribute__((address_space(3))) unsigned int*)(l), 16, 0, 0)

template<int BK>
__device__ __forceinline__ int swz(int row, int s) {
    return (BK == 64) ? (s ^ (row & 7)) : (s ^ ((row >> 1) & 3));
}

// agent-scope grid barrier; cnt[] zeroed by the preceding wconv dispatch.
__device__ __forceinline__ void gridbar(unsigned* cnt, int id) {
    __syncthreads();
    if (threadIdx.x == 0) {
        __hip_atomic_fetch_add(&cnt[id], 1u, __ATOMIC_ACQ_REL,
                               __HIP_MEMORY_SCOPE_AGENT);
        while (__hip_atomic_load(&cnt[id], __ATOMIC_ACQUIRE,
                                 __HIP_MEMORY_SCOPE_AGENT) < (unsigned)GRIDSZ)
            __builtin_amdgcn_s_sleep(2);
    }
    __syncthreads();
    __threadfence();   // reader-side acquire: invalidate L1/L2 before loads
}

// ---------------------------------------------------------------------------
// wconv: weight convert+transpose (R3-proven) + zero cnt[16] and rsum[2048].
// ---------------------------------------------------------------------------
struct WConvArgs {
    const float* src[6];
    bf16*        dst[6];
    int K[6], N[6], Kp[6], t0[7];
    unsigned* cnt;     // 16 words
    float*    rsum;    // 2048 floats
};

__global__ __launch_bounds__(256) void wconv_kernel(WConvArgs a)
{
    __shared__ float Ts[32][33];
    if (blockIdx.x == 0 && threadIdx.x < 16) a.cnt[threadIdx.x] = 0u;
    if (blockIdx.x < 8) a.rsum[blockIdx.x * 256 + threadIdx.x] = 0.f;

    int w = 0;
    while (w < 5 && (int)blockIdx.x >= a.t0[w + 1]) ++w;
    const int rel = blockIdx.x - a.t0[w];
    const int K = a.K[w], N = a.N[w], Kp = a.Kp[w];
    const int nbn = N >> 5;
    const int tk = rel / nbn, tn = rel % nbn;
    const int tx = threadIdx.x & 31, ty = threadIdx.x >> 5;

    const float* src = a.src[w];
    bf16* dst = a.dst[w];

#pragma unroll
    for (int rr = 0; rr < 4; ++rr) {
        const int k = tk * 32 + ty + rr * 8;
        const int n = tn * 32 + tx;
        Ts[ty + rr * 8][tx] = (k < K) ? src[(size_t)k * N + n] : 0.f;
    }
    __syncthreads();
#pragma unroll
    for (int rr = 0; rr < 4; ++rr) {
        const int n = tn * 32 + ty + rr * 8;
        const int kp = tk * 32 + tx;
        dst[(size_t)n * Kp + kp] = __float2bfloat16(Ts[tx][ty + rr * 8]);
    }
}

// ---------------------------------------------------------------------------
// GEMM phase (R3-proven body, grid-strided): C = relu(A @ Wt^T + b).
// ---------------------------------------------------------------------------
template<int BK, int WR, int WC, int MREP, int NREP, bool DENSE, bool FUSE_OUT>
__device__ void gemm_phase(const void* Araw, const bf16* Wt,
                           const float* bias, bf16* C,
                           int M, int N, int K, int ldC, char* lds,
                           const float* w3 = nullptr, float* rsum = nullptr)
{
    constexpr int BM    = WR * MREP * 16;
    constexpr int BN    = WC * NREP * 16;
    constexpr int ROWB  = BK * 2;
    constexpr int SLOTS = BK / 8;
    constexpr int KKS   = BK / 32;
    constexpr int PA    = BM * SLOTS / 256;
    constexpr int PB    = BN * SLOTS / 256;

    bf16* As = (bf16*)lds;
    bf16* Bs = (bf16*)(lds + BM * BK * 2);

    const int t = threadIdx.x;
    const int wid = t >> 6, lane = t & 63;
    const int wr = wid / WC, wc = wid % WC;
    const int lr = lane & 15, q = lane >> 4;
    const int sslot = t % SLOTS;

    const int nbn = N / BN;
    const int ntiles = (M / BM) * nbn;

    for (int tile = blockIdx.x; tile < ntiles; tile += GRIDSZ) {
        const int bm = tile / nbn, bn = tile % nbn;
        const int row0 = bm * BM, n0 = bn * BN;

        const bf16* Ab[PA];
        const bf16* Bb[PB];
#pragma unroll
        for (int p = 0; p < PA; ++p) {
            const int r = (p * 256 + t) / SLOTS;
            if (!DENSE)
                Ab[p] = (const bf16*)Araw + (size_t)(row0 + r) * K +
                        swz<BK>(r, sslot) * 8;
        }
#pragma unroll
        for (int p = 0; p < PB; ++p) {
            const int r = (p * 256 + t) / SLOTS;
            Bb[p] = Wt + (size_t)(n0 + r) * K + swz<BK>(r, sslot) * 8;
        }

        f32x4 acc[MREP][NREP] = {};

        for (int k0 = 0; k0 < K; k0 += BK) {
            if constexpr (DENSE) {
                const float* Df = (const float*)Araw;
#pragma unroll
                for (int idx = t; idx < BM * 32; idx += 256) {
                    const int r = idx >> 5, c = idx & 31;
                    const float v = (c < 13) ? Df[(size_t)(row0 + r) * 13 + c] : 0.f;
                    As[r * 32 + swz<32>(r, c >> 3) * 8 + (c & 7)] =
                        __float2bfloat16(v);
                }
            } else {
#pragma unroll
                for (int p = 0; p < PA; ++p)
                    GLOAD16(Ab[p] + k0, (char*)As + (p * 256 + t) * 16);
            }
#pragma unroll
            for (int p = 0; p < PB; ++p)
                GLOAD16(Bb[p] + k0, (char*)Bs + (p * 256 + t) * 16);
            __syncthreads();

            bf16x8 af[KKS][MREP], bfr[KKS][NREP];
#pragma unroll
            for (int kk = 0; kk < KKS; ++kk) {
#pragma unroll
                for (int m = 0; m < MREP; ++m) {
                    const int r = wr * MREP * 16 + 16 * m + lr;
                    af[kk][m] = *(const bf16x8*)((const char*)As + r * ROWB +
                                                 swz<BK>(r, kk * 4 + q) * 16);
                }
#pragma unroll
                for (int n = 0; n < NREP; ++n) {
                    const int r = wc * NREP * 16 + 16 * n + lr;
                    bfr[kk][n] = *(const bf16x8*)((const char*)Bs + r * ROWB +
                                                  swz<BK>(r, kk * 4 + q) * 16);
                }
            }
#pragma unroll
            for (int kk = 0; kk < KKS; ++kk)
#pragma unroll
                for (int m = 0; m < MREP; ++m)
#pragma unroll
                    for (int n = 0; n < NREP; ++n)
                        acc[m][n] = __builtin_amdgcn_mfma_f32_16x16x32_bf16(
                            af[kk][m], bfr[kk][n], acc[m][n], 0, 0, 0);
            __syncthreads();
        }

        if constexpr (FUSE_OUT) {
            // out-layer fusion: partial = sum_n relu(acc+b)·w3 ; reduce 16
            // lanes; atomicAdd into rsum[row].
#pragma unroll
            for (int m = 0; m < MREP; ++m) {
#pragma unroll
                for (int i = 0; i < 4; ++i) {
                    float val = 0.f;
#pragma unroll
                    for (int n = 0; n < NREP; ++n) {
                        const int col = n0 + wc * NREP * 16 + 16 * n + lr;
                        val += fmaxf(acc[m][n][i] + bias[col], 0.f) * w3[col];
                    }
                    val += __shfl_xor(val, 1);
                    val += __shfl_xor(val, 2);
                    val += __shfl_xor(val, 4);
                    val += __shfl_xor(val, 8);
                    if (lr == 0)
                        atomicAdd(&rsum[row0 + wr * MREP * 16 + 16 * m + q * 4 + i],
                                  val);
                }
            }
        } else {
            // D layout: col = lane&15, row = (lane>>4)*4 + i
#pragma unroll
            for (int n = 0; n < NREP; ++n) {
                const int col = n0 + wc * NREP * 16 + 16 * n + lr;
                const float bv = bias[col];
#pragma unroll
                for (int m = 0; m < MREP; ++m) {
#pragma unroll
                    for (int i = 0; i < 4; ++i) {
                        const int row = row0 + wr * MREP * 16 + 16 * m + q * 4 + i;
                        float v = fmaxf(acc[m][n][i] + bv, 0.f);
                        C[(size_t)row * ldC + col] = __float2bfloat16(v);
                    }
                }
            }
        }
    }
}

// ---------------------------------------------------------------------------
// interact phase: 4 rows/block (512 blocks x 4 = 2048), fused bot (VALU).
// LDS: T[4][27][65] f32 (28080 B) + h1s[4][256] bf16 (2048 B).
// ---------------------------------------------------------------------------
__device__ void interact_phase(const bf16* h1, const bf16* bw2t,
                               const float* bb2, const int* cat,
                               const float* tables, bf16* R, char* lds)
{
    float (*T)[27][65] = (float(*)[27][65])lds;
    bf16  (*h1s)[256]  = (bf16(*)[256])(lds + 28080);

    const int t  = threadIdx.x;
    const int b0 = blockIdx.x * 4;

    // stage h1 rows (4 x 256 bf16): 128 threads x bf16x8
    if (t < 128) {
        const int r = t >> 5, c = (t & 31) * 8;
        *(bf16x8*)&h1s[r][c] = *(const bf16x8*)&h1[(size_t)(b0 + r) * 256 + c];
    }

    // gather: 4 rows x 26 feats x 16 float4
    for (int l = t; l < 4 * NSPARSE * 16; l += 256) {
        const int r   = l / (NSPARSE * 16);
        const int rem = l % (NSPARSE * 16);
        const int j   = rem >> 4, c = (rem & 15) * 4;
        const int idx = cat[(b0 + r) * NSPARSE + j];
        const float4 v =
            *(const float4*)&tables[((size_t)j * VOCAB + idx) * 64 + c];
        float* dst = &T[r][j + 1][c];
        dst[0] = v.x; dst[1] = v.y; dst[2] = v.z; dst[3] = v.w;
    }

    // zero-pad R[:, 415:448)
    for (int z = t; z < 4 * 33; z += 256) {
        const int r = z / 33, c = z % 33;
        R[(size_t)(b0 + r) * RLD + 415 + c] = __float2bfloat16(0.f);
    }
    __syncthreads();

    // bot: 4x64 outputs, one per thread
    {
        const int r = t >> 6, n = t & 63;
        float s = bb2[n];
        const bf16* wrow = bw2t + (size_t)n * 256;
#pragma unroll 8
        for (int k = 0; k < 256; k += 8) {
            const bf16x8 hv = *(const bf16x8*)&h1s[r][k];
            const bf16x8 wv = *(const bf16x8*)&wrow[k];
#pragma unroll
            for (int u = 0; u < 8; ++u)
                s += (float)hv[u] * (float)wv[u];
        }
        s = fmaxf(s, 0.f);
        T[r][0][n] = s;
        R[(size_t)(b0 + r) * RLD + n] = __float2bfloat16(s);
    }
    __syncthreads();

    // pairwise dots: 4 x 351 tasks
    for (int task = t; task < 4 * NPAIR; task += 256) {
        const int r = task / NPAIR, p = task % NPAIR;
        int i = (int)((1.0f + sqrtf(1.0f + 8.0f * (float)p)) * 0.5f);
        while (i * (i - 1) / 2 > p) --i;
        while ((i + 1) * i / 2 <= p) ++i;
        const int j = p - i * (i - 1) / 2;
        float s = 0.f;
#pragma unroll 16
        for (int k = 0; k < 64; ++k) s += T[r][i][k] * T[r][j][k];
        R[(size_t)(b0 + r) * RLD + 64 + p] = __float2bfloat16(s);
    }
}

// ---------------------------------------------------------------------------
struct MArgs {
    const float* dense; const int* cat; const float* tables;
    const float *bb0, *bb1, *bb2, *tb0, *tb1, *tb2, *tw3, *tb3;
    const bf16 *bw0t, *bw1t, *bw2t, *tw0t, *tw1t, *tw2t;
    bf16 *h0, *h1, *R, *r0, *r1;
    unsigned* cnt; float* rsum; float* out;
};

__global__ __launch_bounds__(256, 2) void mega(MArgs a)
{
    __shared__ __align__(16) char lds[30208];

    gemm_phase<32, 2, 2, 2, 2, true,  false>(a.dense, a.bw0t, a.bb0, a.h0,
                                             BATCH, 512, 32, 512, lds);
    gridbar(a.cnt, 0);

    gemm_phase<64, 2, 2, 2, 2, false, false>(a.h0, a.bw1t, a.bb1, a.h1,
                                             BATCH, 256, 512, 256, lds);
    gridbar(a.cnt, 1);

    interact_phase(a.h1, a.bw2t, a.bb2, a.cat, a.tables, a.R, lds);
    gridbar(a.cnt, 2);

    gemm_phase<64, 2, 2, 2, 2, false, false>(a.R, a.tw0t, a.tb0, a.r0,
                                             BATCH, 1024, RLD, 1024, lds);
    gridbar(a.cnt, 3);

    gemm_phase<64, 2, 2, 2, 2, false, false>(a.r0, a.tw1t, a.tb1, a.r1,
                                             BATCH, 512, 1024, 512, lds);
    gridbar(a.cnt, 4);

    gemm_phase<64, 2, 2, 2, 2, false, true >(a.r1, a.tw2t, a.tb2, nullptr,
                                             BATCH, 256, 512, 0, lds,
                                             a.tw3, a.rsum);
    gridbar(a.cnt, 5);

    if (blockIdx.x < 8) {
        const int i = blockIdx.x * 256 + threadIdx.x;
        a.out[i] = 1.f / (1.f + expf(-(a.rsum[i] + a.tb3[0])));
    }
}

// ---------------------------------------------------------------------------
extern "C" void kernel_launch(void* const* d_in, const int* in_sizes, int n_in,
                              void* d_out, int out_size, void* d_ws, size_t ws_size,
                              hipStream_t stream)
{
    const float* dense   = (const float*)d_in[0];
    const int*   cat_idx = (const int*)  d_in[1];
    const float* tables  = (const float*)d_in[2];
    const float* bw0 = (const float*)d_in[3];
    const float* bb0 = (const float*)d_in[4];
    const float* bw1 = (const float*)d_in[5];
    const float* bb1 = (const float*)d_in[6];
    const float* bw2 = (const float*)d_in[7];
    const float* bb2 = (const float*)d_in[8];
    const float* tw0 = (const float*)d_in[9];
    const float* tb0 = (const float*)d_in[10];
    const float* tw1 = (const float*)d_in[11];
    const float* tb1 = (const float*)d_in[12];
    const float* tw2 = (const float*)d_in[13];
    const float* tb2 = (const float*)d_in[14];
    const float* tw3 = (const float*)d_in[15];
    const float* tb3 = (const float*)d_in[16];

    char* pc = (char*)d_ws;
    unsigned* cnt  = (unsigned*)pc; pc += 64;
    float*    rsum = (float*)pc;    pc += 2048 * 4;
    bf16* p = (bf16*)pc;
    bf16* h0   = p; p += (size_t)BATCH * 512;
    bf16* h1   = p; p += (size_t)BATCH * 256;
    bf16* R    = p; p += (size_t)BATCH * RLD;
    bf16* r0   = p; p += (size_t)BATCH * 1024;
    bf16* r1   = p; p += (size_t)BATCH * 512;
    bf16* bw0t = p; p += 512 * 32;
    bf16* bw1t = p; p += 256 * 512;
    bf16* bw2t = p; p += 64 * 256;
    bf16* tw0t = p; p += 1024 * RLD;
    bf16* tw1t = p; p += 512 * 1024;
    bf16* tw2t = p; p += 256 * 512;

    WConvArgs wa;
    wa.src[0] = bw0;  wa.dst[0] = bw0t; wa.K[0] = 13;   wa.N[0] = 512;  wa.Kp[0] = 32;
    wa.src[1] = bw1;  wa.dst[1] = bw1t; wa.K[1] = 512;  wa.N[1] = 256;  wa.Kp[1] = 512;
    wa.src[2] = bw2;  wa.dst[2] = bw2t; wa.K[2] = 256;  wa.N[2] = 64;   wa.Kp[2] = 256;
    wa.src[3] = tw0;  wa.dst[3] = tw0t; wa.K[3] = 415;  wa.N[3] = 1024; wa.Kp[3] = RLD;
    wa.src[4] = tw1;  wa.dst[4] = tw1t; wa.K[4] = 1024; wa.N[4] = 512;  wa.Kp[4] = 1024;
    wa.src[5] = tw2;  wa.dst[5] = tw2t; wa.K[5] = 512;  wa.N[5] = 256;  wa.Kp[5] = 512;
    int tiles = 0;
    for (int w = 0; w < 6; ++w) {
        wa.t0[w] = tiles;
        tiles += (wa.Kp[w] >> 5) * (wa.N[w] >> 5);
    }
    wa.t0[6] = tiles;
    wa.cnt = cnt; wa.rsum = rsum;

    wconv_kernel<<<tiles, 256, 0, stream>>>(wa);

    MArgs ma;
    ma.dense = dense; ma.cat = cat_idx; ma.tables = tables;
    ma.bb0 = bb0; ma.bb1 = bb1; ma.bb2 = bb2;
    ma.tb0 = tb0; ma.tb1 = tb1; ma.tb2 = tb2; ma.tw3 = tw3; ma.tb3 = tb3;
    ma.bw0t = bw0t; ma.bw1t = bw1t; ma.bw2t = bw2t;
    ma.tw0t = tw0t; ma.tw1t = tw1t; ma.tw2t = tw2t;
    ma.h0 = h0; ma.h1 = h1; ma.R = R; ma.r0 = r0; ma.r1 = r1;
    ma.cnt = cnt; ma.rsum = rsum; ma.out = (float*)d_out;

    mega<<<GRIDSZ, 256, 0, stream>>>(ma);
}

// Round 11
// 63.753 us; speedup vs baseline: 9.3937x; 9.3937x over previous
//
#include <hip/hip_runtime.h>
#include <hip/hip_bf16.h>

// DLRM forward, bf16-MFMA, BK=128 single-buffered GEMMs, 8 dispatches.
// B=2048, dense 13, emb 26x100000x64, 27 feats -> 351 pairs,
// top MLP 415(->512 pad)->1024->512->256->1 sigmoid.

#define BATCH 2048
#define VOCAB 100000
#define NSPARSE 26
#define NFEA 27
#define NPAIR 351
#define RLD 512            // padded R row stride (415 -> 512, %128==0)

typedef __attribute__((ext_vector_type(8))) __bf16 bf16x8;
typedef __attribute__((ext_vector_type(4))) float f32x4;
typedef __hip_bfloat16 bf16;

#define GLOAD16(g, l)                                                          \
    __builtin_amdgcn_global_load_lds(                                          \
        (const __attribute__((address_space(1))) unsigned int*)(g),            \
        (__attribute__((address_space(3))) unsigned int*)(l), 16, 0, 0)

template<int BK>
__device__ __forceinline__ int swz(int row, int s) {
    return (BK == 128) ? (s ^ (row & 15))
         : (BK == 64)  ? (s ^ (row & 7))
                       : (s ^ ((row >> 1) & 3));
}

// ---------------------------------------------------------------------------
// bf16 MFMA GEMM: C[M,ldC] = relu(A[M,K] @ Wt[N,K]^T + bias), bf16 I/O,
// f32 accum. 4 waves (WR x WC), wave sub-tile (MREP*16) x (NREP*16).
// Single-buffered LDS, 16B-slot swizzle both sides (BK=128: s^=row&15).
// DENSEPAD: A raw f32 [M][13] staged+padded to K=32 on VALU.
// ---------------------------------------------------------------------------
template<int BK, int WR, int WC, int MREP, int NREP, bool DENSEPAD>
__global__ __launch_bounds__(256) void gemm_bf16(
    const void* __restrict__ Araw,  // bf16 [M][K]  (or f32 [M][13])
    const bf16* __restrict__ Wt,    // [N][K] = W^T
    const float* __restrict__ bias,
    bf16* __restrict__ C,           // [M][ldC]
    int M, int N, int K, int ldC)
{
    constexpr int BM    = WR * MREP * 16;
    constexpr int BN    = WC * NREP * 16;
    constexpr int ROWB  = BK * 2;
    constexpr int SLOTS = BK / 8;
    constexpr int KKS   = BK / 32;
    constexpr int PA    = BM * SLOTS / 256;
    constexpr int PB    = BN * SLOTS / 256;

    __shared__ __align__(16) bf16 As[BM * BK];
    __shared__ __align__(16) bf16 Bs[BN * BK];

    const int t   = threadIdx.x;
    const int nbn = N / BN;
    const int bm  = blockIdx.x / nbn;
    const int bn  = blockIdx.x % nbn;
    const int row0 = bm * BM, n0 = bn * BN;

    const int wid  = t >> 6, lane = t & 63;
    const int wr   = wid / WC, wc = wid % WC;
    const int lr   = lane & 15;
    const int q    = lane >> 4;
    const int sslot = t % SLOTS;

    const bf16* Ab[PA];
    const bf16* Bb[PB];
#pragma unroll
    for (int p = 0; p < PA; ++p) {
        const int r = (p * 256 + t) / SLOTS;
        if (!DENSEPAD)
            Ab[p] = (const bf16*)Araw + (size_t)(row0 + r) * K +
                    swz<BK>(r, sslot) * 8;
    }
#pragma unroll
    for (int p = 0; p < PB; ++p) {
        const int r = (p * 256 + t) / SLOTS;
        Bb[p] = Wt + (size_t)(n0 + r) * K + swz<BK>(r, sslot) * 8;
    }

    f32x4 acc[MREP][NREP] = {};

    for (int k0 = 0; k0 < K; k0 += BK) {
        if constexpr (DENSEPAD) {
            const float* Df = (const float*)Araw;
#pragma unroll
            for (int idx = t; idx < BM * 32; idx += 256) {
                const int r = idx >> 5, c = idx & 31;
                const float v = (c < 13) ? Df[(size_t)(row0 + r) * 13 + c] : 0.f;
                As[r * 32 + swz<32>(r, c >> 3) * 8 + (c & 7)] =
                    __float2bfloat16(v);
            }
        } else {
#pragma unroll
            for (int p = 0; p < PA; ++p)
                GLOAD16(Ab[p] + k0, (char*)As + (p * 256 + t) * 16);
        }
#pragma unroll
        for (int p = 0; p < PB; ++p)
            GLOAD16(Bb[p] + k0, (char*)Bs + (p * 256 + t) * 16);
        __syncthreads();

        bf16x8 af[KKS][MREP], bfr[KKS][NREP];
#pragma unroll
        for (int kk = 0; kk < KKS; ++kk) {
#pragma unroll
            for (int m = 0; m < MREP; ++m) {
                const int r = wr * MREP * 16 + 16 * m + lr;
                af[kk][m] = *(const bf16x8*)((const char*)As + r * ROWB +
                                             swz<BK>(r, kk * 4 + q) * 16);
            }
#pragma unroll
            for (int n = 0; n < NREP; ++n) {
                const int r = wc * NREP * 16 + 16 * n + lr;
                bfr[kk][n] = *(const bf16x8*)((const char*)Bs + r * ROWB +
                                              swz<BK>(r, kk * 4 + q) * 16);
            }
        }
#pragma unroll
        for (int kk = 0; kk < KKS; ++kk)
#pragma unroll
            for (int m = 0; m < MREP; ++m)
#pragma unroll
                for (int n = 0; n < NREP; ++n)
                    acc[m][n] = __builtin_amdgcn_mfma_f32_16x16x32_bf16(
                        af[kk][m], bfr[kk][n], acc[m][n], 0, 0, 0);
        __syncthreads();
    }

    // D layout: col = lane&15, row = (lane>>4)*4 + i
#pragma unroll
    for (int n = 0; n < NREP; ++n) {
        const int col = n0 + wc * NREP * 16 + 16 * n + lr;
        const float bv = bias[col];
#pragma unroll
        for (int m = 0; m < MREP; ++m) {
#pragma unroll
            for (int i = 0; i < 4; ++i) {
                const int row = row0 + wr * MREP * 16 + 16 * m + q * 4 + i;
                float v = fmaxf(acc[m][n][i] + bv, 0.f);
                C[(size_t)row * ldC + col] = __float2bfloat16(v);
            }
        }
    }
}

// ---------------------------------------------------------------------------
// top2 + top3 fused: each block computes 32 rows x ALL 256 cols of
// relu(r1 @ tw2^T + tb2), then out[row] = sigmoid(dot(., tw3) + tb3).
// BK=64, 4 waves N-split (each 32x64), LDS rsum reduce. Grid = 64 blocks.
// ---------------------------------------------------------------------------
__global__ __launch_bounds__(256) void top2_kernel(
    const bf16* __restrict__ A,      // r1 [B][512]
    const bf16* __restrict__ Wt,     // tw2t [256][512]
    const float* __restrict__ bias,  // tb2
    const float* __restrict__ w3,    // tw3 [256]
    const float* __restrict__ b3,    // tb3
    float* __restrict__ out)
{
    constexpr int BK = 64, BM = 32, BN = 256, K = 512;
    constexpr int SLOTS = 8, KKS = 2, PA = 1, PB = 8;

    __shared__ __align__(16) bf16 As[BM * BK];
    __shared__ __align__(16) bf16 Bs[BN * BK];
    __shared__ float rsum[BM];

    const int t = threadIdx.x;
    const int row0 = blockIdx.x * BM;
    const int wc = t >> 6, lane = t & 63;
    const int lr = lane & 15, q = lane >> 4;
    const int sslot = t % SLOTS;

    const bf16* Ab[PA];
    const bf16* Bb[PB];
#pragma unroll
    for (int p = 0; p < PA; ++p) {
        const int r = (p * 256 + t) / SLOTS;
        Ab[p] = A + (size_t)(row0 + r) * K + swz<BK>(r, sslot) * 8;
    }
#pragma unroll
    for (int p = 0; p < PB; ++p) {
        const int r = (p * 256 + t) / SLOTS;
        Bb[p] = Wt + (size_t)r * K + swz<BK>(r, sslot) * 8;
    }

    f32x4 acc[2][4] = {};

    for (int k0 = 0; k0 < K; k0 += BK) {
#pragma unroll
        for (int p = 0; p < PA; ++p)
            GLOAD16(Ab[p] + k0, (char*)As + (p * 256 + t) * 16);
#pragma unroll
        for (int p = 0; p < PB; ++p)
            GLOAD16(Bb[p] + k0, (char*)Bs + (p * 256 + t) * 16);
        __syncthreads();

        bf16x8 af[KKS][2], bfr[KKS][4];
#pragma unroll
        for (int kk = 0; kk < KKS; ++kk) {
#pragma unroll
            for (int m = 0; m < 2; ++m) {
                const int r = 16 * m + lr;
                af[kk][m] = *(const bf16x8*)((const char*)As + r * 128 +
                                             swz<BK>(r, kk * 4 + q) * 16);
            }
#pragma unroll
            for (int n = 0; n < 4; ++n) {
                const int r = wc * 64 + 16 * n + lr;
                bfr[kk][n] = *(const bf16x8*)((const char*)Bs + r * 128 +
                                              swz<BK>(r, kk * 4 + q) * 16);
            }
        }
#pragma unroll
        for (int kk = 0; kk < KKS; ++kk)
#pragma unroll
            for (int m = 0; m < 2; ++m)
#pragma unroll
                for (int n = 0; n < 4; ++n)
                    acc[m][n] = __builtin_amdgcn_mfma_f32_16x16x32_bf16(
                        af[kk][m], bfr[kk][n], acc[m][n], 0, 0, 0);
        __syncthreads();
    }

    if (t < BM) rsum[t] = 0.f;
    __syncthreads();

#pragma unroll
    for (int m = 0; m < 2; ++m) {
#pragma unroll
        for (int i = 0; i < 4; ++i) {
            float val = 0.f;
#pragma unroll
            for (int n = 0; n < 4; ++n) {
                const int col = wc * 64 + 16 * n + lr;
                val += fmaxf(acc[m][n][i] + bias[col], 0.f) * w3[col];
            }
            val += __shfl_xor(val, 1);
            val += __shfl_xor(val, 2);
            val += __shfl_xor(val, 4);
            val += __shfl_xor(val, 8);
            if (lr == 0) atomicAdd(&rsum[16 * m + q * 4 + i], val);
        }
    }
    __syncthreads();
    if (t < BM)
        out[row0 + t] = 1.f / (1.f + expf(-(rsum[t] + b3[0])));
}

// ---------------------------------------------------------------------------
// Weight convert+transpose: dst[n][kp] = bf16(src[k][n]), zero-pad k>=K.
// ---------------------------------------------------------------------------
struct WConvArgs {
    const float* src[6];
    bf16*        dst[6];
    int K[6], N[6], Kp[6], t0[7];
};

__global__ __launch_bounds__(256) void wconv_kernel(WConvArgs a)
{
    __shared__ float Ts[32][33];
    int w = 0;
    while (w < 5 && (int)blockIdx.x >= a.t0[w + 1]) ++w;
    const int rel = blockIdx.x - a.t0[w];
    const int K = a.K[w], N = a.N[w], Kp = a.Kp[w];
    const int nbn = N >> 5;
    const int tk = rel / nbn, tn = rel % nbn;
    const int tx = threadIdx.x & 31, ty = threadIdx.x >> 5;

    const float* src = a.src[w];
    bf16* dst = a.dst[w];

#pragma unroll
    for (int rr = 0; rr < 4; ++rr) {
        const int k = tk * 32 + ty + rr * 8;
        const int n = tn * 32 + tx;
        Ts[ty + rr * 8][tx] = (k < K) ? src[(size_t)k * N + n] : 0.f;
    }
    __syncthreads();
#pragma unroll
    for (int rr = 0; rr < 4; ++rr) {
        const int n = tn * 32 + ty + rr * 8;
        const int kp = tk * 32 + tx;
        dst[(size_t)n * Kp + kp] = __float2bfloat16(Ts[tx][ty + rr * 8]);
    }
}

// ---------------------------------------------------------------------------
// Embedding gather + pairwise dots. One block per batch row (R3/R6-proven).
// bot (bf16) sits in R[b][0:64]; writes R[b][64+p], zero-pads [415,512).
// ---------------------------------------------------------------------------
__global__ __launch_bounds__(256) void interact_kernel(
    const int* __restrict__ cat_idx, const float* __restrict__ tables,
    bf16* __restrict__ R)
{
    __shared__ float T[NFEA][64 + 1];

    const int b    = blockIdx.x;
    const int t    = threadIdx.x;
    const int g    = t >> 6;
    const int lane = t & 63;
    bf16* Rrow = R + (size_t)b * RLD;

    for (int f = g; f < NFEA; f += 4) {
        if (f == 0) {
            T[0][lane] = __bfloat162float(Rrow[lane]);
        } else {
            const int j   = f - 1;
            const int idx = cat_idx[b * NSPARSE + j];
            T[f][lane] = tables[((size_t)j * VOCAB + idx) * 64 + lane];
        }
    }
    __syncthreads();

    if (t < RLD - 415) Rrow[415 + t] = __float2bfloat16(0.f);

    for (int p = t; p < NPAIR; p += 256) {
        int i = (int)((1.0f + sqrtf(1.0f + 8.0f * (float)p)) * 0.5f);
        while (i * (i - 1) / 2 > p) --i;
        while ((i + 1) * i / 2 <= p) ++i;
        const int j = p - i * (i - 1) / 2;
        float s = 0.f;
#pragma unroll 16
        for (int k = 0; k < 64; ++k) s += T[i][k] * T[j][k];
        Rrow[64 + p] = __float2bfloat16(s);
    }
}

// ---------------------------------------------------------------------------
extern "C" void kernel_launch(void* const* d_in, const int* in_sizes, int n_in,
                              void* d_out, int out_size, void* d_ws, size_t ws_size,
                              hipStream_t stream)
{
    const float* dense   = (const float*)d_in[0];
    const int*   cat_idx = (const int*)  d_in[1];
    const float* tables  = (const float*)d_in[2];
    const float* bw0 = (const float*)d_in[3];
    const float* bb0 = (const float*)d_in[4];
    const float* bw1 = (const float*)d_in[5];
    const float* bb1 = (const float*)d_in[6];
    const float* bw2 = (const float*)d_in[7];
    const float* bb2 = (const float*)d_in[8];
    const float* tw0 = (const float*)d_in[9];
    const float* tb0 = (const float*)d_in[10];
    const float* tw1 = (const float*)d_in[11];
    const float* tb1 = (const float*)d_in[12];
    const float* tw2 = (const float*)d_in[13];
    const float* tb2 = (const float*)d_in[14];
    const float* tw3 = (const float*)d_in[15];
    const float* tb3 = (const float*)d_in[16];

    bf16* p = (bf16*)d_ws;
    bf16* h0   = p; p += (size_t)BATCH * 512;
    bf16* h1   = p; p += (size_t)BATCH * 256;
    bf16* R    = p; p += (size_t)BATCH * RLD;
    bf16* r0   = p; p += (size_t)BATCH * 1024;
    bf16* r1   = p; p += (size_t)BATCH * 512;
    bf16* bw0t = p; p += 512 * 32;
    bf16* bw1t = p; p += 256 * 512;
    bf16* bw2t = p; p += 64 * 256;
    bf16* tw0t = p; p += 1024 * RLD;
    bf16* tw1t = p; p += 512 * 1024;
    bf16* tw2t = p; p += 256 * 512;
    float* out = (float*)d_out;

    WConvArgs wa;
    wa.src[0] = bw0;  wa.dst[0] = bw0t; wa.K[0] = 13;   wa.N[0] = 512;  wa.Kp[0] = 32;
    wa.src[1] = bw1;  wa.dst[1] = bw1t; wa.K[1] = 512;  wa.N[1] = 256;  wa.Kp[1] = 512;
    wa.src[2] = bw2;  wa.dst[2] = bw2t; wa.K[2] = 256;  wa.N[2] = 64;   wa.Kp[2] = 256;
    wa.src[3] = tw0;  wa.dst[3] = tw0t; wa.K[3] = 415;  wa.N[3] = 1024; wa.Kp[3] = RLD;
    wa.src[4] = tw1;  wa.dst[4] = tw1t; wa.K[4] = 1024; wa.N[4] = 512;  wa.Kp[4] = 1024;
    wa.src[5] = tw2;  wa.dst[5] = tw2t; wa.K[5] = 512;  wa.N[5] = 256;  wa.Kp[5] = 512;
    int tiles = 0;
    for (int w = 0; w < 6; ++w) {
        wa.t0[w] = tiles;
        tiles += (wa.Kp[w] >> 5) * (wa.N[w] >> 5);
    }
    wa.t0[6] = tiles;

    wconv_kernel<<<tiles, 256, 0, stream>>>(wa);

    // bottom MLP
    gemm_bf16<32, 2, 2, 2, 2, true ><<<(BATCH / 64) * (512 / 64), 256, 0, stream>>>(
        dense, bw0t, bb0, h0, BATCH, 512, 32, 512);
    gemm_bf16<128, 2, 2, 2, 2, false><<<(BATCH / 64) * (256 / 64), 256, 0, stream>>>(
        h0, bw1t, bb1, h1, BATCH, 256, 512, 256);
    gemm_bf16<128, 2, 2, 2, 2, false><<<(BATCH / 64) * (64 / 64), 256, 0, stream>>>(
        h1, bw2t, bb2, R, BATCH, 64, 256, RLD);   // bot -> R[:, :64]

    interact_kernel<<<BATCH, 256, 0, stream>>>(cat_idx, tables, R);

    // top MLP
    gemm_bf16<128, 2, 2, 2, 2, false><<<(BATCH / 64) * (1024 / 64), 256, 0, stream>>>(
        R, tw0t, tb0, r0, BATCH, 1024, RLD, 1024);
    gemm_bf16<128, 2, 2, 2, 2, false><<<(BATCH / 64) * (512 / 64), 256, 0, stream>>>(
        r0, tw1t, tb1, r1, BATCH, 512, 1024, 512);
    top2_kernel<<<BATCH / 32, 256, 0, stream>>>(r1, tw2t, tb2, tw3, tb3, out);
}